// Round 4
// baseline (375.050 us; speedup 1.0000x reference)
//
#include <hip/hip_runtime.h>
#include <hip/hip_bf16.h>
#include <hip/hip_cooperative_groups.h>
#include <math.h>

namespace cg = cooperative_groups;

#define NEG_SLOPE 0.2f
#define GAT_EPS 1e-16f

constexpr int NN = 50000;   // nodes
constexpr int NE = 800000;  // raw edges
constexpr int EP = NE + NN; // edges incl. self loops = 850000
constexpr int NB = (NN + 255) / 256; // scan blocks = 196

// CSR-build geometry
constexpr int PB  = 128;                  // histogram blocks
constexpr int PT  = 1024;                 // threads per histogram block
constexpr int CH  = (EP + PB - 1) / PB;   // edges per block = 6641
constexpr int NCH = 4;                    // block-row chunks
constexpr int BPC = PB / NCH;             // 32 block-rows per chunk

constexpr int GB1 = (NN + 63) / 64;       // gemm1 blocks = 782
constexpr int GB2 = (NN + 63) / 64;       // gemm2 blocks = 782
constexpr int AB  = (EP + 255) / 256;     // alpha blocks = 3321

__device__ inline void edge_sd(const int* __restrict__ ei, int i, int& s, int& d) {
    if (i < NE) { s = ei[i]; d = ei[NE + i]; }
    else        { s = d = i - NE; }
}

__device__ inline float bflo(unsigned int h) { return __uint_as_float(h << 16); }
__device__ inline float bfhi(unsigned int h) { return __uint_as_float(h & 0xffff0000u); }

// ---------------- CSR build ----------------
// P1: per-block LDS u8 histogram; ds_add_rtn gives within-block rank.
__global__ __launch_bounds__(PT) void k_p1_hist(const int* __restrict__ ei,
                                                float* __restrict__ out0,
                                                unsigned char* __restrict__ hist,
                                                unsigned char* __restrict__ rank8) {
    __shared__ unsigned int sh[NN / 4]; // 12500 words = 50KB
    int b = blockIdx.x, t = threadIdx.x;
    for (int w = t; w < NN / 4; w += PT) sh[w] = 0u;
    __syncthreads();
    int i0 = b * CH;
    int iend = i0 + CH; if (iend > EP) iend = EP;
    for (int i = i0 + t; i < iend; i += PT) {
        int s, d; edge_sd(ei, i, s, d);
        __builtin_nontemporal_store((float)s, &out0[i]);
        __builtin_nontemporal_store((float)d, &out0[EP + i]);
        int sft = (d & 3) * 8;
        unsigned int old = atomicAdd(&sh[d >> 2], 1u << sft); // LDS atomic, CU-local
        __builtin_nontemporal_store((unsigned char)(old >> sft), &rank8[i]);
    }
    __syncthreads();
    unsigned int* hw = (unsigned int*)(hist + (size_t)b * NN);
    for (int w = t; w < NN / 4; w += PT) hw[w] = sh[w];
}

// All four scan phases in ONE cooperative kernel (grid = NB x 256).
// Phase A = p2 with register-pipelined loads (32 independent loads, scan in regs).
__global__ __launch_bounds__(256) void k_scans_coop(
    unsigned char* __restrict__ hist, unsigned char* __restrict__ chunksum,
    unsigned char* __restrict__ chunkoff, int* __restrict__ rowptr,
    int* __restrict__ bsum, int* __restrict__ boff) {
    __shared__ int sh[256];
    cg::grid_group grid = cg::this_grid();
    int t = threadIdx.x;
    int g = blockIdx.x * 256 + t;
    constexpr int G = NB * 256; // 50176
    // phase A: per-(node,chunk) exclusive scan down BPC block-rows
    for (int u = g; u < NN * NCH; u += G) {
        int n = u % NN, c = u / NN;
        int base = (c * BPC) * NN + n;
        unsigned int v[BPC];
#pragma unroll
        for (int b = 0; b < BPC; ++b) v[b] = hist[base + b * NN]; // independent loads
        unsigned int run = 0;
#pragma unroll
        for (int b = 0; b < BPC; ++b) { unsigned int x = v[b]; v[b] = run; run += x; }
#pragma unroll
        for (int b = 0; b < BPC; ++b) hist[base + b * NN] = (unsigned char)v[b];
        chunksum[n * NCH + c] = (unsigned char)run;
    }
    grid.sync();
    // phase B: per-256-node block scan (old scan1)
    {
        int i = g, vv = 0;
        if (i < NN) {
            unsigned int cs = *(const unsigned int*)&chunksum[i * 4];
            unsigned int c0 = cs & 0xffu, c1 = (cs >> 8) & 0xffu;
            unsigned int c2 = (cs >> 16) & 0xffu, c3 = cs >> 24;
            unsigned int o1 = c0, o2 = c0 + c1, o3 = c0 + c1 + c2;
            *(unsigned int*)&chunkoff[i * 4] = (o1 << 8) | (o2 << 16) | (o3 << 24);
            vv = (int)(o3 + c3);
        }
        sh[t] = vv; __syncthreads();
        for (int off = 1; off < 256; off <<= 1) {
            int xx = (t >= off) ? sh[t - off] : 0;
            __syncthreads();
            sh[t] += xx;
            __syncthreads();
        }
        if (i < NN) rowptr[i] = sh[t] - vv;
        if (t == 255) bsum[blockIdx.x] = sh[255];
    }
    grid.sync();
    // phase C: block-total scan (old scan2), block 0 only
    if (blockIdx.x == 0) {
        int vv = (t < NB) ? bsum[t] : 0;
        sh[t] = vv; __syncthreads();
        for (int off = 1; off < 256; off <<= 1) {
            int xx = (t >= off) ? sh[t - off] : 0;
            __syncthreads();
            sh[t] += xx;
            __syncthreads();
        }
        if (t < NB) boff[t] = sh[t] - vv;
    }
    grid.sync();
    // phase D: add block offsets (old scan3)
    if (g < NN) rowptr[g] += boff[g >> 8];
    if (g == 0) rowptr[NN] = EP;
}

// ---- standalone fallbacks (used only if cooperative launch is refused) ----
__global__ __launch_bounds__(256) void k_p2_scan(unsigned char* __restrict__ hist,
                                                 unsigned char* __restrict__ chunksum) {
    int n = blockIdx.x * 256 + threadIdx.x;
    int c = blockIdx.y;
    if (n >= NN) return;
    int base = (c * BPC) * NN + n;
    unsigned int v[BPC];
#pragma unroll
    for (int b = 0; b < BPC; ++b) v[b] = hist[base + b * NN];
    unsigned int run = 0;
#pragma unroll
    for (int b = 0; b < BPC; ++b) { unsigned int x = v[b]; v[b] = run; run += x; }
#pragma unroll
    for (int b = 0; b < BPC; ++b) hist[base + b * NN] = (unsigned char)v[b];
    chunksum[n * NCH + c] = (unsigned char)run;
}

__global__ void k_scan1(const unsigned char* __restrict__ chunksum,
                        unsigned char* __restrict__ chunkoff,
                        int* __restrict__ rowptr, int* __restrict__ bsum) {
    __shared__ int sh[256];
    int t = threadIdx.x, i = blockIdx.x * 256 + t;
    int v = 0;
    if (i < NN) {
        unsigned int cs = *(const unsigned int*)&chunksum[i * 4];
        unsigned int c0 = cs & 0xffu, c1 = (cs >> 8) & 0xffu;
        unsigned int c2 = (cs >> 16) & 0xffu, c3 = cs >> 24;
        unsigned int o1 = c0, o2 = c0 + c1, o3 = c0 + c1 + c2;
        *(unsigned int*)&chunkoff[i * 4] = (o1 << 8) | (o2 << 16) | (o3 << 24);
        v = (int)(o3 + c3);
    }
    sh[t] = v; __syncthreads();
    for (int off = 1; off < 256; off <<= 1) {
        int x = (t >= off) ? sh[t - off] : 0;
        __syncthreads();
        sh[t] += x;
        __syncthreads();
    }
    if (i < NN) rowptr[i] = sh[t] - v;
    if (t == 255) bsum[blockIdx.x] = sh[255];
}

__global__ void k_scan2(int* __restrict__ bsum, int* __restrict__ boff) {
    __shared__ int sh[256];
    int t = threadIdx.x;
    int v = (t < NB) ? bsum[t] : 0;
    sh[t] = v; __syncthreads();
    for (int off = 1; off < 256; off <<= 1) {
        int x = (t >= off) ? sh[t - off] : 0;
        __syncthreads();
        sh[t] += x;
        __syncthreads();
    }
    if (t < NB) boff[t] = sh[t] - v;
}

__global__ void k_scan3(int* __restrict__ rowptr, const int* __restrict__ boff) {
    int i = blockIdx.x * blockDim.x + threadIdx.x;
    if (i < NN) rowptr[i] += boff[i >> 8];
    if (i == 0) rowptr[NN] = EP;
}

// ---------------- dense GEMM body (device fn, shared by fat + plain kernels) ----------------
struct alignas(8) bh4 { __hip_bfloat16 a, b, c, d; };

__device__ inline void fma4(float4& acc, float x, const float4& w) {
    acc.x = fmaf(x, w.x, acc.x);
    acc.y = fmaf(x, w.y, acc.y);
    acc.z = fmaf(x, w.z, acc.z);
    acc.w = fmaf(x, w.w, acc.w);
}

template <int FIN, int FOUT, int NPB>
__device__ __forceinline__ void gemm_body(float* sX, float* sWt, int bid,
                                          const float* __restrict__ in,
                                          const float* __restrict__ W,
                                          const float* __restrict__ avs,
                                          const float* __restrict__ avd,
                                          __hip_bfloat16* __restrict__ H,
                                          float* __restrict__ as_,
                                          float* __restrict__ ad_, int n) {
    constexpr int TF = FOUT / 4;
    constexpr int XS = FIN + 4;
    constexpr int WS = FOUT + 4;
    int tid = threadIdx.x;
    for (int idx = tid; idx < FIN * FOUT; idx += 256) {
        int f = idx % FOUT, k = idx / FOUT;
        sWt[k * WS + f] = W[f * FIN + k];
    }
    int nb = bid * NPB;
    for (int idx = tid; idx < NPB * (FIN / 4); idx += 256) {
        int node = idx / (FIN / 4), kq = idx % (FIN / 4);
        int g = nb + node;
        float4 v = make_float4(0.f, 0.f, 0.f, 0.f);
        if (g < n) v = *(const float4*)&in[(size_t)g * FIN + kq * 4];
        *(float4*)&sX[node * XS + kq * 4] = v;
    }
    __syncthreads();

    int fq = tid % TF, ng = tid / TF;
    int n0 = ng * 4;
    float4 acc0 = make_float4(0.f, 0.f, 0.f, 0.f);
    float4 acc1 = acc0, acc2 = acc0, acc3 = acc0;
    for (int k = 0; k < FIN; k += 4) {
        float4 w0 = *(const float4*)&sWt[(k + 0) * WS + fq * 4];
        float4 w1 = *(const float4*)&sWt[(k + 1) * WS + fq * 4];
        float4 w2 = *(const float4*)&sWt[(k + 2) * WS + fq * 4];
        float4 w3 = *(const float4*)&sWt[(k + 3) * WS + fq * 4];
        float4 x0 = *(const float4*)&sX[(n0 + 0) * XS + k];
        float4 x1 = *(const float4*)&sX[(n0 + 1) * XS + k];
        float4 x2 = *(const float4*)&sX[(n0 + 2) * XS + k];
        float4 x3 = *(const float4*)&sX[(n0 + 3) * XS + k];
        fma4(acc0, x0.x, w0); fma4(acc0, x0.y, w1); fma4(acc0, x0.z, w2); fma4(acc0, x0.w, w3);
        fma4(acc1, x1.x, w0); fma4(acc1, x1.y, w1); fma4(acc1, x1.z, w2); fma4(acc1, x1.w, w3);
        fma4(acc2, x2.x, w0); fma4(acc2, x2.y, w1); fma4(acc2, x2.z, w2); fma4(acc2, x2.w, w3);
        fma4(acc3, x3.x, w0); fma4(acc3, x3.y, w1); fma4(acc3, x3.z, w2); fma4(acc3, x3.w, w3);
    }
    float4 accs[4] = {acc0, acc1, acc2, acc3};
    float4 vs4 = *(const float4*)&avs[fq * 4];
    float4 vd4 = *(const float4*)&avd[fq * 4];
#pragma unroll
    for (int j = 0; j < 4; ++j) {
        int g = nb + n0 + j;
        float ps = accs[j].x * vs4.x + accs[j].y * vs4.y + accs[j].z * vs4.z + accs[j].w * vs4.w;
        float pd = accs[j].x * vd4.x + accs[j].y * vd4.y + accs[j].z * vd4.z + accs[j].w * vd4.w;
#pragma unroll
        for (int off = TF / 2; off; off >>= 1) {
            ps += __shfl_down(ps, off, TF);
            pd += __shfl_down(pd, off, TF);
        }
        if (g < n) {
            if (fq == 0) { as_[g] = ps; ad_[g] = pd; }
            bh4 o;
            o.a = __float2bfloat16(accs[j].x);
            o.b = __float2bfloat16(accs[j].y);
            o.c = __float2bfloat16(accs[j].z);
            o.d = __float2bfloat16(accs[j].w);
            *(bh4*)&H[(size_t)g * FOUT + fq * 4] = o;
        }
    }
}

// fill body (device fn): same PB-chunk geometry as p1, 256 threads
__device__ __forceinline__ void fill_body(int b, const int* __restrict__ ei,
                                          const unsigned char* __restrict__ rank8,
                                          const unsigned char* __restrict__ hist,
                                          const unsigned char* __restrict__ chunkoff,
                                          const int* __restrict__ rowptr,
                                          unsigned short* __restrict__ col) {
    int c = b / BPC;
    const unsigned char* __restrict__ hrow = hist + (size_t)b * NN;
    int i0 = b * CH;
    int iend = i0 + CH; if (iend > EP) iend = EP;
    for (int i = i0 + threadIdx.x; i < iend; i += 256) {
        int s, d; edge_sd(ei, i, s, d);
        int pos = rowptr[d] + (int)chunkoff[d * 4 + c] + (int)hrow[d] + (int)rank8[i];
        col[pos] = (unsigned short)s;
    }
}

// FAT kernel 1: blocks [0,PB) = CSR fill, blocks [PB, PB+GB1) = layer-1 GEMM.
// Independent work; fill blocks first so both finish before attn1.
__global__ __launch_bounds__(256) void k_fill_gemm1(
    const int* __restrict__ ei, const unsigned char* __restrict__ rank8,
    const unsigned char* __restrict__ hist, const unsigned char* __restrict__ chunkoff,
    const int* __restrict__ rowptr, unsigned short* __restrict__ col,
    const float* __restrict__ x, const float* __restrict__ W1,
    const float* __restrict__ avs, const float* __restrict__ avd,
    __hip_bfloat16* __restrict__ H, float* __restrict__ as_, float* __restrict__ ad_) {
    __shared__ float sX[64 * 132];   // NPB*(FIN+4)
    __shared__ float sWt[128 * 68];  // FIN*(FOUT+4)
    int bid = blockIdx.x;
    if (bid < PB) {
        fill_body(bid, ei, rank8, hist, chunkoff, rowptr, col);
    } else {
        gemm_body<128, 64, 64>(sX, sWt, bid - PB, x, W1, avs, avd, H, as_, ad_, NN);
    }
}

// alpha body (device fn)
__device__ __forceinline__ void alpha_body(int b, const int* __restrict__ ei,
                                           const float* __restrict__ as_,
                                           const float* __restrict__ ad_,
                                           const float* __restrict__ inv,
                                           float* __restrict__ out_alpha) {
    int i = b * 256 + threadIdx.x;
    if (i >= EP) return;
    int s, d; edge_sd(ei, i, s, d);
    float v = as_[s] + ad_[d];
    v = v > 0.f ? v : NEG_SLOPE * v;
    __builtin_nontemporal_store(__expf(v) * inv[d], &out_alpha[i]);
}

// FAT kernel 2: blocks [0,GB2) = layer-2 GEMM (writes as_B/ad_B), blocks
// [GB2, GB2+AB) = alpha output (reads layer-1 as_A/ad_A/inv). No overlap.
__global__ __launch_bounds__(256) void k_gemm2_alpha(
    const float* __restrict__ agg, const float* __restrict__ W2,
    const float* __restrict__ avs, const float* __restrict__ avd,
    __hip_bfloat16* __restrict__ H, float* __restrict__ asB, float* __restrict__ adB,
    const int* __restrict__ ei, const float* __restrict__ asA,
    const float* __restrict__ adA, const float* __restrict__ inv,
    float* __restrict__ out_alpha) {
    __shared__ float sX[64 * 68];
    __shared__ float sWt[64 * 68];
    int bid = blockIdx.x;
    if (bid < GB2) {
        gemm_body<64, 64, 64>(sX, sWt, bid, agg, W2, avs, avd, H, asB, adB, NN);
    } else {
        alpha_body(bid - GB2, ei, asA, adA, inv, out_alpha);
    }
}

// plain GEMM kernel (layer 3)
template <int FIN, int FOUT, int NPB>
__global__ __launch_bounds__(256) void k_gemm_t(const float* __restrict__ in,
                                                const float* __restrict__ W,
                                                const float* __restrict__ avs,
                                                const float* __restrict__ avd,
                                                __hip_bfloat16* __restrict__ H,
                                                float* __restrict__ as_,
                                                float* __restrict__ ad_, int n) {
    __shared__ float sX[NPB * (FIN + 4)];
    __shared__ float sWt[FIN * (FOUT + 4)];
    gemm_body<FIN, FOUT, NPB>(sX, sWt, blockIdx.x, in, W, avs, avd, H, as_, ad_, n);
}

// ---------------- fused per-node softmax + aggregate (one wave per node) ----------------
template <int FOUT, bool RELU, bool WRITE_INV>
__global__ __launch_bounds__(256) void k_node_attn(
    const int* __restrict__ rowptr, const unsigned short* __restrict__ col,
    const float* __restrict__ as_, const float* __restrict__ ad_,
    const __hip_bfloat16* __restrict__ H, const float* __restrict__ bias,
    float* __restrict__ outp, float* __restrict__ inv_out) {
    int wid = (blockIdx.x * blockDim.x + threadIdx.x) >> 6; // node
    int lane = threadIdx.x & 63;
    if (wid >= NN) return;
    int start = rowptr[wid], end = rowptr[wid + 1];
    float adv = ad_[wid];
    const uint2* __restrict__ H4 = (const uint2*)H;

    float sloc = 0.f;
    float ax = 0.f, ay = 0.f, az = 0.f, aw = 0.f;
    for (int c = start; c < end; c += 64) {
        int e = c + lane;
        float p = 0.f;
        int sc = 0;
        if (e < end) {
            sc = (int)col[e];
            float v = as_[sc] + adv;
            v = v > 0.f ? v : NEG_SLOPE * v;
            p = __expf(v);
        }
        sloc += p;
        int cnt = end - c; if (cnt > 64) cnt = 64;
        if (FOUT == 64) {
            int q = lane >> 4, fl = lane & 15;      // row = 16 uint2
            int j = 0;
            for (; j + 32 <= cnt; j += 32) {        // 8 gathers in flight / lane
                float pp[8]; int ss[8]; uint2 hh[8];
#pragma unroll
                for (int k = 0; k < 8; ++k) {
                    int ek = j + 4 * k + q;
                    pp[k] = __shfl(p, ek);
                    ss[k] = __shfl(sc, ek);
                }
#pragma unroll
                for (int k = 0; k < 8; ++k) hh[k] = H4[((size_t)ss[k] << 4) + fl];
#pragma unroll
                for (int k = 0; k < 8; ++k) {
                    ax = fmaf(pp[k], bflo(hh[k].x), ax);
                    ay = fmaf(pp[k], bfhi(hh[k].x), ay);
                    az = fmaf(pp[k], bflo(hh[k].y), az);
                    aw = fmaf(pp[k], bfhi(hh[k].y), aw);
                }
            }
            for (; j + 8 <= cnt; j += 8) {
                int e0 = j + q, e1 = j + 4 + q;
                float p0 = __shfl(p, e0), p1 = __shfl(p, e1);
                int s0 = __shfl(sc, e0), s1 = __shfl(sc, e1);
                uint2 h0 = H4[((size_t)s0 << 4) + fl];
                uint2 h1 = H4[((size_t)s1 << 4) + fl];
                ax = fmaf(p0, bflo(h0.x), ax); ay = fmaf(p0, bfhi(h0.x), ay);
                az = fmaf(p0, bflo(h0.y), az); aw = fmaf(p0, bfhi(h0.y), aw);
                ax = fmaf(p1, bflo(h1.x), ax); ay = fmaf(p1, bfhi(h1.x), ay);
                az = fmaf(p1, bflo(h1.y), az); aw = fmaf(p1, bfhi(h1.y), aw);
            }
            for (; j < cnt; j += 4) {
                int e0 = j + q;
                float p0 = __shfl(p, e0);
                int   s0 = __shfl(sc, e0);
                uint2 h0 = H4[((size_t)s0 << 4) + fl];
                ax = fmaf(p0, bflo(h0.x), ax); ay = fmaf(p0, bfhi(h0.x), ay);
                az = fmaf(p0, bflo(h0.y), az); aw = fmaf(p0, bfhi(h0.y), aw);
            }
        } else { // FOUT == 32: row = 8 uint2, 8 edges/step
            int oc = lane >> 3, fl = lane & 7;
            int j = 0;
            for (; j + 32 <= cnt; j += 32) {
                float pp[4]; int ss[4]; uint2 hh[4];
#pragma unroll
                for (int k = 0; k < 4; ++k) {
                    int ek = j + 8 * k + oc;
                    pp[k] = __shfl(p, ek);
                    ss[k] = __shfl(sc, ek);
                }
#pragma unroll
                for (int k = 0; k < 4; ++k) hh[k] = H4[((size_t)ss[k] << 3) + fl];
#pragma unroll
                for (int k = 0; k < 4; ++k) {
                    ax = fmaf(pp[k], bflo(hh[k].x), ax);
                    ay = fmaf(pp[k], bfhi(hh[k].x), ay);
                    az = fmaf(pp[k], bflo(hh[k].y), az);
                    aw = fmaf(pp[k], bfhi(hh[k].y), aw);
                }
            }
            for (; j < cnt; j += 8) {
                int e0 = j + oc;
                float p0 = __shfl(p, e0);
                int   s0 = __shfl(sc, e0);
                uint2 h0 = H4[((size_t)s0 << 3) + fl];
                ax = fmaf(p0, bflo(h0.x), ax); ay = fmaf(p0, bfhi(h0.x), ay);
                az = fmaf(p0, bflo(h0.y), az); aw = fmaf(p0, bfhi(h0.y), aw);
            }
        }
    }
    for (int off = 32; off; off >>= 1) sloc += __shfl_xor(sloc, off);
    float inv = 1.f / (sloc + GAT_EPS);
    if (WRITE_INV && lane == 0) inv_out[wid] = inv;

    if (FOUT == 64) {
        ax += __shfl_xor(ax, 16); ay += __shfl_xor(ay, 16);
        az += __shfl_xor(az, 16); aw += __shfl_xor(aw, 16);
        ax += __shfl_xor(ax, 32); ay += __shfl_xor(ay, 32);
        az += __shfl_xor(az, 32); aw += __shfl_xor(aw, 32);
        if (lane < 16) {
            float4 bb = *(const float4*)&bias[lane * 4];
            float o0 = bb.x + ax * inv;
            float o1 = bb.y + ay * inv;
            float o2 = bb.z + az * inv;
            float o3 = bb.w + aw * inv;
            if (RELU) {
                o0 = fmaxf(o0, 0.f); o1 = fmaxf(o1, 0.f);
                o2 = fmaxf(o2, 0.f); o3 = fmaxf(o3, 0.f);
            }
            *(float4*)&outp[((size_t)wid << 6) + lane * 4] = make_float4(o0, o1, o2, o3);
        }
    } else {
        ax += __shfl_xor(ax, 8);  ay += __shfl_xor(ay, 8);
        az += __shfl_xor(az, 8);  aw += __shfl_xor(aw, 8);
        ax += __shfl_xor(ax, 16); ay += __shfl_xor(ay, 16);
        az += __shfl_xor(az, 16); aw += __shfl_xor(aw, 16);
        ax += __shfl_xor(ax, 32); ay += __shfl_xor(ay, 32);
        az += __shfl_xor(az, 32); aw += __shfl_xor(aw, 32);
        if (lane < 8) {
            float4 bb = *(const float4*)&bias[lane * 4];
            float o0 = bb.x + ax * inv;
            float o1 = bb.y + ay * inv;
            float o2 = bb.z + az * inv;
            float o3 = bb.w + aw * inv;
            if (RELU) {
                o0 = fmaxf(o0, 0.f); o1 = fmaxf(o1, 0.f);
                o2 = fmaxf(o2, 0.f); o3 = fmaxf(o3, 0.f);
            }
            *(float4*)&outp[((size_t)wid << 5) + lane * 4] = make_float4(o0, o1, o2, o3);
        }
    }
}

extern "C" void kernel_launch(void* const* d_in, const int* in_sizes, int n_in,
                              void* d_out, int out_size, void* d_ws, size_t ws_size,
                              hipStream_t stream) {
    const float* x  = (const float*)d_in[0];
    const int*   ei = (const int*)d_in[1];
    const float* W1 = (const float*)d_in[2];
    const float* as1 = (const float*)d_in[3];
    const float* ad1 = (const float*)d_in[4];
    const float* b1 = (const float*)d_in[5];
    const float* W2 = (const float*)d_in[6];
    const float* as2 = (const float*)d_in[7];
    const float* ad2 = (const float*)d_in[8];
    const float* b2 = (const float*)d_in[9];
    const float* W3 = (const float*)d_in[10];
    const float* as3 = (const float*)d_in[11];
    const float* ad3 = (const float*)d_in[12];
    const float* b3 = (const float*)d_in[13];

    float* out = (float*)d_out;
    float* out_edges = out;                 // [2, EP]
    float* out_alpha = out + 2 * EP;        // [EP]
    float* out_final = out + 3 * EP;        // [N, 32] = 6.4MB, written only by attn3

    char* w = (char*)d_ws;
    size_t o = 0;
    auto alloc = [&](size_t bytes) { void* p = w + o; o = (o + bytes + 15) & ~15ull; return p; };
    float* asA = (float*)alloc((size_t)NN * 4);
    float* adA = (float*)alloc((size_t)NN * 4);
    float* asB = (float*)alloc((size_t)NN * 4);
    float* adB = (float*)alloc((size_t)NN * 4);
    float* inv = (float*)alloc((size_t)NN * 4);
    __hip_bfloat16* H = (__hip_bfloat16*)alloc((size_t)NN * 64 * 2); // 6.4MB
    int* rowptr = (int*)alloc((size_t)(NN + 1) * 4);
    unsigned char* rank8 = (unsigned char*)alloc((size_t)EP);        // 0.85MB
    unsigned short* col  = (unsigned short*)alloc((size_t)EP * 2);   // 1.7MB
    unsigned char* chunksum = (unsigned char*)alloc((size_t)NN * 4); // 200KB
    unsigned char* chunkoff = (unsigned char*)alloc((size_t)NN * 4); // 200KB
    int* bsum = (int*)alloc(1024);
    int* boff = (int*)alloc(1024);

    const size_t aggBytes  = (size_t)NN * 64 * 4;       // 12.8MB
    const size_t histBytes = (size_t)PB * NN;           // 6.4MB
    float* agg = (ws_size >= o + aggBytes)
        ? (float*)(w + o)
        : (float*)d_in[0];  // safe: layer-1 GEMM consumes x before agg first written
    unsigned char* hist = (ws_size >= o + aggBytes + histBytes)
        ? (unsigned char*)(w + o + aggBytes)
        : (unsigned char*)out_final; // dead until the final attn dispatch

    // --- CSR build: p1 -> fused cooperative scans (fallback: 4 plain launches) ---
    k_p1_hist<<<PB, PT, 0, stream>>>(ei, out_edges, hist, rank8);
    {
        void* args[] = {(void*)&hist, (void*)&chunksum, (void*)&chunkoff,
                        (void*)&rowptr, (void*)&bsum, (void*)&boff};
        hipError_t e = hipLaunchCooperativeKernel((const void*)k_scans_coop, dim3(NB),
                                                  dim3(256), args, 0, stream);
        if (e != hipSuccess) {
            (void)hipGetLastError();
            k_p2_scan<<<dim3(NB, NCH), 256, 0, stream>>>(hist, chunksum);
            k_scan1<<<NB, 256, 0, stream>>>(chunksum, chunkoff, rowptr, bsum);
            k_scan2<<<1, 256, 0, stream>>>(bsum, boff);
            k_scan3<<<NB, 256, 0, stream>>>(rowptr, boff);
        }
    }

    const int nblk = (NN * 64 + 255) / 256;

    // FAT: CSR fill (128 blocks, first) || layer-1 GEMM (782 blocks)
    k_fill_gemm1<<<PB + GB1, 256, 0, stream>>>(ei, rank8, hist, chunkoff, rowptr, col,
                                               x, W1, as1, ad1, H, asA, adA);
    // attn layer 1 (writes inv for the alpha pass)
    k_node_attn<64, true, true><<<nblk, 256, 0, stream>>>(rowptr, col, asA, adA, H, b1,
                                                          agg, inv);
    // FAT: layer-2 GEMM (writes asB/adB; 782 blocks, first) || alpha output
    // (reads layer-1 asA/adA/inv; 3321 blocks)
    k_gemm2_alpha<<<GB2 + AB, 256, 0, stream>>>(agg, W2, as2, ad2, H, asB, adB,
                                                ei, asA, adA, inv, out_alpha);
    // attn layer 2
    k_node_attn<64, true, false><<<nblk, 256, 0, stream>>>(rowptr, col, asB, adB, H, b2,
                                                           agg, nullptr);
    // layer 3: 64 -> 32
    k_gemm_t<64, 32, 128><<<(NN + 127) / 128, 256, 0, stream>>>(agg, W3, as3, ad3, H,
                                                                asA, adA, NN);
    k_node_attn<32, false, false><<<nblk, 256, 0, stream>>>(rowptr, col, asA, adA, H, b3,
                                                            out_final, nullptr);
}

// Round 5
// 292.678 us; speedup vs baseline: 1.2814x; 1.2814x over previous
//
#include <hip/hip_runtime.h>
#include <hip/hip_bf16.h>
#include <math.h>

#define NEG_SLOPE 0.2f
#define GAT_EPS 1e-16f

constexpr int NN = 50000;   // nodes
constexpr int NE = 800000;  // raw edges
constexpr int EP = NE + NN; // edges incl. self loops = 850000
constexpr int NB = (NN + 255) / 256; // scan blocks = 196

// CSR-build geometry
constexpr int PB  = 128;                  // histogram blocks
constexpr int PT  = 1024;                 // threads per histogram block
constexpr int CH  = (EP + PB - 1) / PB;   // edges per block = 6641
constexpr int NCH = 4;                    // block-row chunks
constexpr int BPC = PB / NCH;             // 32 block-rows per chunk

__device__ inline void edge_sd(const int* __restrict__ ei, int i, int& s, int& d) {
    if (i < NE) { s = ei[i]; d = ei[NE + i]; }
    else        { s = d = i - NE; }
}

__device__ inline float bflo(unsigned int h) { return __uint_as_float(h << 16); }
__device__ inline float bfhi(unsigned int h) { return __uint_as_float(h & 0xffff0000u); }

// ---------------- CSR build, zero device-scope atomics ----------------
// P1: per-block LDS u8 histogram; ds_add_rtn gives within-block rank.
// Fused: coalesced NT dump of the edge list output chunk.
__global__ __launch_bounds__(PT) void k_p1_hist(const int* __restrict__ ei,
                                                float* __restrict__ out0,
                                                unsigned char* __restrict__ hist,
                                                unsigned char* __restrict__ rank8) {
    __shared__ unsigned int sh[NN / 4]; // 12500 words = 50KB
    int b = blockIdx.x, t = threadIdx.x;
    for (int w = t; w < NN / 4; w += PT) sh[w] = 0u;
    __syncthreads();
    int i0 = b * CH;
    int iend = i0 + CH; if (iend > EP) iend = EP;
    for (int i = i0 + t; i < iend; i += PT) {
        int s, d; edge_sd(ei, i, s, d);
        __builtin_nontemporal_store((float)s, &out0[i]);
        __builtin_nontemporal_store((float)d, &out0[EP + i]);
        int sft = (d & 3) * 8;
        unsigned int old = atomicAdd(&sh[d >> 2], 1u << sft); // LDS atomic, CU-local
        __builtin_nontemporal_store((unsigned char)(old >> sft), &rank8[i]);
    }
    __syncthreads();
    unsigned int* hw = (unsigned int*)(hist + (size_t)b * NN);
    for (int w = t; w < NN / 4; w += PT) hw[w] = sh[w];
}

// Fused p2+scan1: thread t owns node n. Scans all PB hist rows for n
// (register-pipelined: 32 independent u8 loads per chunk, scan in regs,
// store back), builds packed chunkoff + per-node total, then block-scans
// 256 totals -> partial rowptr + per-block sum.
__global__ __launch_bounds__(256) void k_p2s1(unsigned char* __restrict__ hist,
                                              unsigned char* __restrict__ chunkoff,
                                              int* __restrict__ rowptr,
                                              int* __restrict__ bsum) {
    __shared__ int sh[256];
    int t = threadIdx.x;
    int n = blockIdx.x * 256 + t;
    int v = 0;
    if (n < NN) {
        unsigned int runs[NCH];
#pragma unroll
        for (int c = 0; c < NCH; ++c) {
            size_t base = (size_t)(c * BPC) * NN + n;
            unsigned int vv[BPC];
#pragma unroll
            for (int b = 0; b < BPC; ++b) vv[b] = hist[base + (size_t)b * NN];
            unsigned int run = 0;
#pragma unroll
            for (int b = 0; b < BPC; ++b) { unsigned int x = vv[b]; vv[b] = run; run += x; }
#pragma unroll
            for (int b = 0; b < BPC; ++b) hist[base + (size_t)b * NN] = (unsigned char)vv[b];
            runs[c] = run;
        }
        unsigned int o1 = runs[0], o2 = o1 + runs[1], o3 = o2 + runs[2];
        *(unsigned int*)&chunkoff[(size_t)n * 4] = (o1 << 8) | (o2 << 16) | (o3 << 24);
        v = (int)(o3 + runs[3]);
    }
    sh[t] = v; __syncthreads();
    for (int off = 1; off < 256; off <<= 1) {
        int x = (t >= off) ? sh[t - off] : 0;
        __syncthreads();
        sh[t] += x;
        __syncthreads();
    }
    if (n < NN) rowptr[n] = sh[t] - v;
    if (t == 255) bsum[blockIdx.x] = sh[255];
}

// Fused scan2+scan3: every block scans the (tiny) bsum array in LDS itself,
// takes its own exclusive offset, applies to its 256-node rowptr tile.
__global__ __launch_bounds__(256) void k_s23(int* __restrict__ rowptr,
                                             const int* __restrict__ bsum) {
    __shared__ int sh[256];
    int t = threadIdx.x;
    int v = (t < NB) ? bsum[t] : 0;
    sh[t] = v; __syncthreads();
    for (int off = 1; off < 256; off <<= 1) {
        int x = (t >= off) ? sh[t - off] : 0;
        __syncthreads();
        sh[t] += x;
        __syncthreads();
    }
    int blk = blockIdx.x;
    int off = (blk == 0) ? 0 : sh[blk - 1]; // inclusive scan -> exclusive offset
    int n = blk * 256 + t;
    if (n < NN) rowptr[n] += off;
    if (n == 0) rowptr[NN] = EP;
}

// CSR fill, grid-strided for full occupancy; hist row from edge index.
__global__ __launch_bounds__(256) void k_fill(const int* __restrict__ ei,
                                              const unsigned char* __restrict__ rank8,
                                              const unsigned char* __restrict__ hist,
                                              const unsigned char* __restrict__ chunkoff,
                                              const int* __restrict__ rowptr,
                                              unsigned short* __restrict__ col) {
    int i = blockIdx.x * 256 + threadIdx.x;
    if (i >= EP) return;
    int b = i / CH;   // hist block-row (const divide -> magic mul)
    int c = b / BPC;  // chunk
    int s, d; edge_sd(ei, i, s, d);
    int pos = rowptr[d] + (int)chunkoff[d * 4 + c] + (int)hist[(size_t)b * NN + d]
            + (int)rank8[i];
    col[pos] = (unsigned short)s;
}

// edge-order alpha output (coalesced NT write; score arrays L2-resident)
__global__ void k_alpha_out(const int* __restrict__ ei, const float* __restrict__ as_,
                            const float* __restrict__ ad_, const float* __restrict__ inv,
                            float* __restrict__ out_alpha) {
    int i = blockIdx.x * blockDim.x + threadIdx.x;
    if (i >= EP) return;
    int s, d; edge_sd(ei, i, s, d);
    float v = as_[s] + ad_[d];
    v = v > 0.f ? v : NEG_SLOPE * v;
    __builtin_nontemporal_store(__expf(v) * inv[d], &out_alpha[i]);
}

// ---------------- dense GEMM + fused alpha scores ----------------
struct alignas(8) bh4 { __hip_bfloat16 a, b, c, d; };

__device__ inline void fma4(float4& acc, float x, const float4& w) {
    acc.x = fmaf(x, w.x, acc.x);
    acc.y = fmaf(x, w.y, acc.y);
    acc.z = fmaf(x, w.z, acc.z);
    acc.w = fmaf(x, w.w, acc.w);
}

template <int FIN, int FOUT, int NPB>
__global__ __launch_bounds__(256) void k_gemm_t(const float* __restrict__ in,
                                                const float* __restrict__ W,
                                                const float* __restrict__ avs,
                                                const float* __restrict__ avd,
                                                __hip_bfloat16* __restrict__ H,
                                                float* __restrict__ as_,
                                                float* __restrict__ ad_, int n) {
    constexpr int TF = FOUT / 4;
    constexpr int XS = FIN + 4;
    constexpr int WS = FOUT + 4;
    __shared__ float sX[NPB * XS];
    __shared__ float sWt[FIN * WS];
    int tid = threadIdx.x;
    for (int idx = tid; idx < FIN * FOUT; idx += 256) {
        int f = idx % FOUT, k = idx / FOUT;
        sWt[k * WS + f] = W[f * FIN + k];
    }
    int nb = blockIdx.x * NPB;
    for (int idx = tid; idx < NPB * (FIN / 4); idx += 256) {
        int node = idx / (FIN / 4), kq = idx % (FIN / 4);
        int g = nb + node;
        float4 v = make_float4(0.f, 0.f, 0.f, 0.f);
        if (g < n) v = *(const float4*)&in[(size_t)g * FIN + kq * 4];
        *(float4*)&sX[node * XS + kq * 4] = v;
    }
    __syncthreads();

    int fq = tid % TF, ng = tid / TF;
    int n0 = ng * 4;
    float4 acc0 = make_float4(0.f, 0.f, 0.f, 0.f);
    float4 acc1 = acc0, acc2 = acc0, acc3 = acc0;
    for (int k = 0; k < FIN; k += 4) {
        float4 w0 = *(const float4*)&sWt[(k + 0) * WS + fq * 4];
        float4 w1 = *(const float4*)&sWt[(k + 1) * WS + fq * 4];
        float4 w2 = *(const float4*)&sWt[(k + 2) * WS + fq * 4];
        float4 w3 = *(const float4*)&sWt[(k + 3) * WS + fq * 4];
        float4 x0 = *(const float4*)&sX[(n0 + 0) * XS + k];
        float4 x1 = *(const float4*)&sX[(n0 + 1) * XS + k];
        float4 x2 = *(const float4*)&sX[(n0 + 2) * XS + k];
        float4 x3 = *(const float4*)&sX[(n0 + 3) * XS + k];
        fma4(acc0, x0.x, w0); fma4(acc0, x0.y, w1); fma4(acc0, x0.z, w2); fma4(acc0, x0.w, w3);
        fma4(acc1, x1.x, w0); fma4(acc1, x1.y, w1); fma4(acc1, x1.z, w2); fma4(acc1, x1.w, w3);
        fma4(acc2, x2.x, w0); fma4(acc2, x2.y, w1); fma4(acc2, x2.z, w2); fma4(acc2, x2.w, w3);
        fma4(acc3, x3.x, w0); fma4(acc3, x3.y, w1); fma4(acc3, x3.z, w2); fma4(acc3, x3.w, w3);
    }
    float4 accs[4] = {acc0, acc1, acc2, acc3};
    float4 vs4 = *(const float4*)&avs[fq * 4];
    float4 vd4 = *(const float4*)&avd[fq * 4];
#pragma unroll
    for (int j = 0; j < 4; ++j) {
        int g = nb + n0 + j;
        float ps = accs[j].x * vs4.x + accs[j].y * vs4.y + accs[j].z * vs4.z + accs[j].w * vs4.w;
        float pd = accs[j].x * vd4.x + accs[j].y * vd4.y + accs[j].z * vd4.z + accs[j].w * vd4.w;
#pragma unroll
        for (int off = TF / 2; off; off >>= 1) {
            ps += __shfl_down(ps, off, TF);
            pd += __shfl_down(pd, off, TF);
        }
        if (g < n) {
            if (fq == 0) { as_[g] = ps; ad_[g] = pd; }
            bh4 o;
            o.a = __float2bfloat16(accs[j].x);
            o.b = __float2bfloat16(accs[j].y);
            o.c = __float2bfloat16(accs[j].z);
            o.d = __float2bfloat16(accs[j].w);
            *(bh4*)&H[(size_t)g * FOUT + fq * 4] = o;
        }
    }
}

// ---------------- fused per-node softmax + aggregate (one wave per node) ----------------
template <int FOUT, bool RELU, bool WRITE_INV>
__global__ __launch_bounds__(256) void k_node_attn(
    const int* __restrict__ rowptr, const unsigned short* __restrict__ col,
    const float* __restrict__ as_, const float* __restrict__ ad_,
    const __hip_bfloat16* __restrict__ H, const float* __restrict__ bias,
    float* __restrict__ outp, float* __restrict__ inv_out) {
    int wid = (blockIdx.x * blockDim.x + threadIdx.x) >> 6; // node
    int lane = threadIdx.x & 63;
    if (wid >= NN) return;
    int start = rowptr[wid], end = rowptr[wid + 1];
    float adv = ad_[wid];
    const uint2* __restrict__ H4 = (const uint2*)H;

    float sloc = 0.f;
    float ax = 0.f, ay = 0.f, az = 0.f, aw = 0.f;
    for (int c = start; c < end; c += 64) {
        int e = c + lane;
        float p = 0.f;
        int sc = 0;
        if (e < end) {
            sc = (int)col[e];
            float v = as_[sc] + adv;
            v = v > 0.f ? v : NEG_SLOPE * v;
            p = __expf(v);
        }
        sloc += p;
        int cnt = end - c; if (cnt > 64) cnt = 64;
        if (FOUT == 64) {
            int q = lane >> 4, fl = lane & 15;      // row = 16 uint2
            int j = 0;
            for (; j + 32 <= cnt; j += 32) {        // 8 gathers in flight / lane
                float pp[8]; int ss[8]; uint2 hh[8];
#pragma unroll
                for (int k = 0; k < 8; ++k) {
                    int ek = j + 4 * k + q;
                    pp[k] = __shfl(p, ek);
                    ss[k] = __shfl(sc, ek);
                }
#pragma unroll
                for (int k = 0; k < 8; ++k) hh[k] = H4[((size_t)ss[k] << 4) + fl];
#pragma unroll
                for (int k = 0; k < 8; ++k) {
                    ax = fmaf(pp[k], bflo(hh[k].x), ax);
                    ay = fmaf(pp[k], bfhi(hh[k].x), ay);
                    az = fmaf(pp[k], bflo(hh[k].y), az);
                    aw = fmaf(pp[k], bfhi(hh[k].y), aw);
                }
            }
            for (; j + 8 <= cnt; j += 8) {
                int e0 = j + q, e1 = j + 4 + q;
                float p0 = __shfl(p, e0), p1 = __shfl(p, e1);
                int s0 = __shfl(sc, e0), s1 = __shfl(sc, e1);
                uint2 h0 = H4[((size_t)s0 << 4) + fl];
                uint2 h1 = H4[((size_t)s1 << 4) + fl];
                ax = fmaf(p0, bflo(h0.x), ax); ay = fmaf(p0, bfhi(h0.x), ay);
                az = fmaf(p0, bflo(h0.y), az); aw = fmaf(p0, bfhi(h0.y), aw);
                ax = fmaf(p1, bflo(h1.x), ax); ay = fmaf(p1, bfhi(h1.x), ay);
                az = fmaf(p1, bflo(h1.y), az); aw = fmaf(p1, bfhi(h1.y), aw);
            }
            for (; j < cnt; j += 4) {
                int e0 = j + q;
                float p0 = __shfl(p, e0);
                int   s0 = __shfl(sc, e0);
                uint2 h0 = H4[((size_t)s0 << 4) + fl];
                ax = fmaf(p0, bflo(h0.x), ax); ay = fmaf(p0, bfhi(h0.x), ay);
                az = fmaf(p0, bflo(h0.y), az); aw = fmaf(p0, bfhi(h0.y), aw);
            }
        } else { // FOUT == 32: row = 8 uint2, 8 edges/step
            int oc = lane >> 3, fl = lane & 7;
            int j = 0;
            for (; j + 32 <= cnt; j += 32) {
                float pp[4]; int ss[4]; uint2 hh[4];
#pragma unroll
                for (int k = 0; k < 4; ++k) {
                    int ek = j + 8 * k + oc;
                    pp[k] = __shfl(p, ek);
                    ss[k] = __shfl(sc, ek);
                }
#pragma unroll
                for (int k = 0; k < 4; ++k) hh[k] = H4[((size_t)ss[k] << 3) + fl];
#pragma unroll
                for (int k = 0; k < 4; ++k) {
                    ax = fmaf(pp[k], bflo(hh[k].x), ax);
                    ay = fmaf(pp[k], bfhi(hh[k].x), ay);
                    az = fmaf(pp[k], bflo(hh[k].y), az);
                    aw = fmaf(pp[k], bfhi(hh[k].y), aw);
                }
            }
            for (; j < cnt; j += 8) {
                int e0 = j + oc;
                float p0 = __shfl(p, e0);
                int   s0 = __shfl(sc, e0);
                uint2 h0 = H4[((size_t)s0 << 3) + fl];
                ax = fmaf(p0, bflo(h0.x), ax); ay = fmaf(p0, bfhi(h0.x), ay);
                az = fmaf(p0, bflo(h0.y), az); aw = fmaf(p0, bfhi(h0.y), aw);
            }
        }
    }
    for (int off = 32; off; off >>= 1) sloc += __shfl_xor(sloc, off);
    float inv = 1.f / (sloc + GAT_EPS);
    if (WRITE_INV && lane == 0) inv_out[wid] = inv;

    if (FOUT == 64) {
        ax += __shfl_xor(ax, 16); ay += __shfl_xor(ay, 16);
        az += __shfl_xor(az, 16); aw += __shfl_xor(aw, 16);
        ax += __shfl_xor(ax, 32); ay += __shfl_xor(ay, 32);
        az += __shfl_xor(az, 32); aw += __shfl_xor(aw, 32);
        if (lane < 16) {
            float4 bb = *(const float4*)&bias[lane * 4];
            float o0 = bb.x + ax * inv;
            float o1 = bb.y + ay * inv;
            float o2 = bb.z + az * inv;
            float o3 = bb.w + aw * inv;
            if (RELU) {
                o0 = fmaxf(o0, 0.f); o1 = fmaxf(o1, 0.f);
                o2 = fmaxf(o2, 0.f); o3 = fmaxf(o3, 0.f);
            }
            *(float4*)&outp[((size_t)wid << 6) + lane * 4] = make_float4(o0, o1, o2, o3);
        }
    } else {
        ax += __shfl_xor(ax, 8);  ay += __shfl_xor(ay, 8);
        az += __shfl_xor(az, 8);  aw += __shfl_xor(aw, 8);
        ax += __shfl_xor(ax, 16); ay += __shfl_xor(ay, 16);
        az += __shfl_xor(az, 16); aw += __shfl_xor(aw, 16);
        ax += __shfl_xor(ax, 32); ay += __shfl_xor(ay, 32);
        az += __shfl_xor(az, 32); aw += __shfl_xor(aw, 32);
        if (lane < 8) {
            float4 bb = *(const float4*)&bias[lane * 4];
            float o0 = bb.x + ax * inv;
            float o1 = bb.y + ay * inv;
            float o2 = bb.z + az * inv;
            float o3 = bb.w + aw * inv;
            if (RELU) {
                o0 = fmaxf(o0, 0.f); o1 = fmaxf(o1, 0.f);
                o2 = fmaxf(o2, 0.f); o3 = fmaxf(o3, 0.f);
            }
            *(float4*)&outp[((size_t)wid << 5) + lane * 4] = make_float4(o0, o1, o2, o3);
        }
    }
}

extern "C" void kernel_launch(void* const* d_in, const int* in_sizes, int n_in,
                              void* d_out, int out_size, void* d_ws, size_t ws_size,
                              hipStream_t stream) {
    const float* x  = (const float*)d_in[0];
    const int*   ei = (const int*)d_in[1];
    const float* W1 = (const float*)d_in[2];
    const float* as1 = (const float*)d_in[3];
    const float* ad1 = (const float*)d_in[4];
    const float* b1 = (const float*)d_in[5];
    const float* W2 = (const float*)d_in[6];
    const float* as2 = (const float*)d_in[7];
    const float* ad2 = (const float*)d_in[8];
    const float* b2 = (const float*)d_in[9];
    const float* W3 = (const float*)d_in[10];
    const float* as3 = (const float*)d_in[11];
    const float* ad3 = (const float*)d_in[12];
    const float* b3 = (const float*)d_in[13];

    float* out = (float*)d_out;
    float* out_edges = out;                 // [2, EP]
    float* out_alpha = out + 2 * EP;        // [EP]
    float* out_final = out + 3 * EP;        // [N, 32] = 6.4MB, written only by attn3

    char* w = (char*)d_ws;
    size_t o = 0;
    auto alloc = [&](size_t bytes) { void* p = w + o; o = (o + bytes + 15) & ~15ull; return p; };
    float* as_ = (float*)alloc((size_t)NN * 4);
    float* ad_ = (float*)alloc((size_t)NN * 4);
    float* inv = (float*)alloc((size_t)NN * 4);
    __hip_bfloat16* H = (__hip_bfloat16*)alloc((size_t)NN * 64 * 2); // 6.4MB
    int* rowptr = (int*)alloc((size_t)(NN + 1) * 4);
    unsigned char* rank8 = (unsigned char*)alloc((size_t)EP);        // 0.85MB
    unsigned short* col  = (unsigned short*)alloc((size_t)EP * 2);   // 1.7MB
    unsigned char* chunkoff = (unsigned char*)alloc((size_t)NN * 4); // 200KB
    int* bsum = (int*)alloc(1024);

    const size_t aggBytes  = (size_t)NN * 64 * 4;       // 12.8MB
    const size_t histBytes = (size_t)PB * NN;           // 6.4MB
    float* agg = (ws_size >= o + aggBytes)
        ? (float*)(w + o)
        : (float*)d_in[0];  // safe: layer-1 GEMM consumes x before agg first written
    unsigned char* hist = (ws_size >= o + aggBytes + histBytes)
        ? (unsigned char*)(w + o + aggBytes)
        : (unsigned char*)out_final; // dead until the final attn dispatch

    // --- CSR build: 4 launches ---
    k_p1_hist<<<PB, PT, 0, stream>>>(ei, out_edges, hist, rank8);
    k_p2s1<<<NB, 256, 0, stream>>>(hist, chunkoff, rowptr, bsum);
    k_s23<<<NB, 256, 0, stream>>>(rowptr, bsum);
    k_fill<<<(EP + 255) / 256, 256, 0, stream>>>(ei, rank8, hist, chunkoff, rowptr, col);

    const int nblk = (NN * 64 + 255) / 256;

    // layer 1: 128 -> 64, ReLU fused; stores inv[] for the alpha pass
    k_gemm_t<128, 64, 64><<<(NN + 63) / 64, 256, 0, stream>>>(x, W1, as1, ad1, H, as_, ad_, NN);
    k_node_attn<64, true, true><<<nblk, 256, 0, stream>>>(rowptr, col, as_, ad_, H, b1,
                                                          agg, inv);
    k_alpha_out<<<(EP + 255) / 256, 256, 0, stream>>>(ei, as_, ad_, inv, out_alpha);

    // layer 2: 64 -> 64, ReLU fused
    k_gemm_t<64, 64, 64><<<(NN + 63) / 64, 256, 0, stream>>>(agg, W2, as2, ad2, H, as_, ad_, NN);
    k_node_attn<64, true, false><<<nblk, 256, 0, stream>>>(rowptr, col, as_, ad_, H, b2,
                                                           agg, nullptr);

    // layer 3: 64 -> 32, straight into d_out chunk 2
    k_gemm_t<64, 32, 128><<<(NN + 127) / 128, 256, 0, stream>>>(agg, W3, as3, ad3, H, as_, ad_,
                                                                NN);
    k_node_attn<32, false, false><<<nblk, 256, 0, stream>>>(rowptr, col, as_, ad_, H, b3,
                                                            out_final, nullptr);
}